// Round 5
// baseline (384.548 us; speedup 1.0000x reference)
//
#include <hip/hip_runtime.h>
#include <hip/hip_bf16.h>

typedef __attribute__((ext_vector_type(8))) short bf16x8;
typedef __attribute__((ext_vector_type(4))) float f32x4;

// Problem constants
#define SPLITN 32
#define DDIM   256
#define UNITS  256
#define BROWS  4096

static __device__ __forceinline__ ushort f2bf(float f) {
    __hip_bfloat16 h = __float2bfloat16(f);
    return *reinterpret_cast<ushort*>(&h);
}

static __device__ __forceinline__ bf16x8 cvt8(f32x4 lo, f32x4 hi) {
    union { uint u32[4]; bf16x8 v; } r;
    r.u32[0] = (uint)f2bf(lo[0]) | ((uint)f2bf(lo[1]) << 16);
    r.u32[1] = (uint)f2bf(lo[2]) | ((uint)f2bf(lo[3]) << 16);
    r.u32[2] = (uint)f2bf(hi[0]) | ((uint)f2bf(hi[1]) << 16);
    r.u32[3] = (uint)f2bf(hi[2]) | ((uint)f2bf(hi[3]) << 16);
    return r.v;
}

// ---------------------------------------------------------------------------
// Prep: W[s][d][u] fp32  ->  Wt[s][u][d] bf16   (LDS-tiled transpose+convert)
// grid (4,4,32) x 256 threads, 64x64 tiles
// ---------------------------------------------------------------------------
__global__ __launch_bounds__(256) void wt_prep(const float* __restrict__ W,
                                               ushort* __restrict__ Wt) {
    __shared__ float tile[64][65];   // +1 pad: conflict-free transpose
    const int s  = blockIdx.z;
    const int d0 = blockIdx.y * 64;
    const int u0 = blockIdx.x * 64;
    const int t  = threadIdx.x;

    const float* Ws = W + s * 65536;
    #pragma unroll
    for (int i = 0; i < 4; ++i) {
        int f  = t + i * 256;        // 1024 float4 chunks
        int d  = f >> 4;             // 16 float4 per 64-wide row
        int uq = f & 15;
        f32x4 v = *reinterpret_cast<const f32x4*>(Ws + (d0 + d) * 256 + u0 + uq * 4);
        tile[d][uq * 4 + 0] = v[0];
        tile[d][uq * 4 + 1] = v[1];
        tile[d][uq * 4 + 2] = v[2];
        tile[d][uq * 4 + 3] = v[3];
    }
    __syncthreads();

    ushort* Wts = Wt + s * 65536;
    #pragma unroll
    for (int i = 0; i < 4; ++i) {
        int g  = t + i * 256;
        int u  = g >> 4;
        int dq = g & 15;
        uint lo = (uint)f2bf(tile[dq * 4 + 0][u]) | ((uint)f2bf(tile[dq * 4 + 1][u]) << 16);
        uint hi = (uint)f2bf(tile[dq * 4 + 2][u]) | ((uint)f2bf(tile[dq * 4 + 3][u]) << 16);
        uint2 val; val.x = lo; val.y = hi;
        *reinterpret_cast<uint2*>(Wts + (u0 + u) * 256 + d0 + dq * 4) = val;
    }
}

// ---------------------------------------------------------------------------
// High-occupancy streaming GEMM. NO LDS, NO barriers, no vmcnt(0).
// Grid 2048 blocks (32 splits x 64 row-chunks), 256 threads = 4 waves.
// Per wave: 16 rows x 256 cols. A (16x256) loaded once -> 32 VGPRs bf16
// (x read exactly once). B streamed from L2 (W bf16 = 512 KB per XCD after
// swizzle; the 4 waves of a block read identical B addresses -> L1 hits).
// 64-col chunks, k-pipeline double-buffered with static indices.
// VGPR ~96, __launch_bounds__(256,5) -> 5 waves/SIMD, 20 waves/CU.
// ---------------------------------------------------------------------------
__global__ __launch_bounds__(256, 5) void lc_gemm(const float* __restrict__ x,
                                                  const ushort* __restrict__ Wt,
                                                  const float* __restrict__ bias,
                                                  float* __restrict__ out) {
    // bijective XCD swizzle: 2048 % 8 == 0; each XCD gets 4 splits (B L2-hot)
    const int bid = blockIdx.x;
    const int sw  = (bid & 7) * 256 + (bid >> 3);
    const int s   = sw >> 6;            // split
    const int rc  = sw & 63;            // row-chunk (64 rows)
    const int t   = threadIdx.x;
    const int w   = t >> 6, l = t & 63;
    const int lr  = l & 15, lg = l >> 4;
    const int m0  = rc * 64 + w * 16;   // this wave's 16 rows

    // ---- A: load 16x256 fp32 once, convert -> 8 x bf16x8 (32 VGPRs) ----
    // A-frag mapping (verified R2-R4): lane holds row=l&15, k=(l>>4)*8+j
    const float* xp = x + (long)(m0 + lr) * 8192 + s * 256 + lg * 8;
    bf16x8 Af[8];
    #pragma unroll
    for (int k = 0; k < 8; ++k) {
        f32x4 lo = *reinterpret_cast<const f32x4*>(xp + k * 32);
        f32x4 hi = *reinterpret_cast<const f32x4*>(xp + k * 32 + 4);
        Af[k] = cvt8(lo, hi);
    }

    const ushort* wb = Wt + s * 65536 + lr * 256 + lg * 8;  // B-frag base (col=lr)
    const float*  bb = bias + s * 256 + lr;
    float*        ob = out + (long)(m0 + lg * 4) * 8192 + s * 256 + lr;

    for (int c = 0; c < 4; ++c) {       // 4 chunks of 64 cols
        const ushort* wbc = wb + c * (64 * 256);

        float bv[4];
        #pragma unroll
        for (int ni = 0; ni < 4; ++ni) bv[ni] = bb[c * 64 + ni * 16];

        f32x4 acc[4];
        #pragma unroll
        for (int ni = 0; ni < 4; ++ni) {
            f32x4 z = {0.f, 0.f, 0.f, 0.f};
            acc[ni] = z;
        }

        // k-pipeline: B0/B1 double buffer, everything statically indexed
        bf16x8 B0[4], B1[4];
        #pragma unroll
        for (int ni = 0; ni < 4; ++ni)
            B0[ni] = *reinterpret_cast<const bf16x8*>(wbc + ni * (16 * 256));

        #pragma unroll
        for (int k = 0; k < 8; k += 2) {
            #pragma unroll
            for (int ni = 0; ni < 4; ++ni)
                B1[ni] = *reinterpret_cast<const bf16x8*>(wbc + ni * (16 * 256) + (k + 1) * 32);
            #pragma unroll
            for (int ni = 0; ni < 4; ++ni)
                acc[ni] = __builtin_amdgcn_mfma_f32_16x16x32_bf16(
                    Af[k], B0[ni], acc[ni], 0, 0, 0);
            if (k + 2 < 8) {
                #pragma unroll
                for (int ni = 0; ni < 4; ++ni)
                    B0[ni] = *reinterpret_cast<const bf16x8*>(wbc + ni * (16 * 256) + (k + 2) * 32);
            }
            #pragma unroll
            for (int ni = 0; ni < 4; ++ni)
                acc[ni] = __builtin_amdgcn_mfma_f32_16x16x32_bf16(
                    Af[k + 1], B1[ni], acc[ni], 0, 0, 0);
        }

        // epilogue: bias + relu, plain dword stores (L2 write-combines rows)
        // C/D layout (verified): col = lane&15, row = (lane>>4)*4 + reg
        #pragma unroll
        for (int ni = 0; ni < 4; ++ni)
            #pragma unroll
            for (int rr = 0; rr < 4; ++rr) {
                float v = fmaxf(acc[ni][rr] + bv[ni], 0.f);
                ob[(long)rr * 8192 + c * 64 + ni * 16] = v;
            }
    }
}

// ---------------------------------------------------------------------------
// Fallback (only if workspace is too small for Wt): naive fp32 dot per output
// ---------------------------------------------------------------------------
__global__ void naive_lc(const float* __restrict__ x, const float* __restrict__ W,
                         const float* __restrict__ b, float* __restrict__ out,
                         int total) {
    int i = blockIdx.x * blockDim.x + threadIdx.x;
    if (i >= total) return;
    int u = i & 255;
    int s = (i >> 8) & 31;
    int bi = i >> 13;
    const float* xr = x + (long)bi * 8192 + s * 256;
    const float* wc = W + s * 65536 + u;
    float acc = 0.f;
    #pragma unroll 4
    for (int d = 0; d < 256; ++d) acc += xr[d] * wc[d * 256];
    out[i] = fmaxf(acc + b[s * 256 + u], 0.f);
}

extern "C" void kernel_launch(void* const* d_in, const int* in_sizes, int n_in,
                              void* d_out, int out_size, void* d_ws, size_t ws_size,
                              hipStream_t stream) {
    const float* x = (const float*)d_in[0];
    const float* W = (const float*)d_in[1];
    const float* b = (const float*)d_in[2];
    float* out = (float*)d_out;

    const size_t wt_bytes = (size_t)SPLITN * DDIM * UNITS * sizeof(ushort); // 4 MiB
    if (ws_size >= wt_bytes) {
        ushort* Wt = (ushort*)d_ws;
        wt_prep<<<dim3(4, 4, 32), 256, 0, stream>>>(W, Wt);
        lc_gemm<<<dim3(2048), 256, 0, stream>>>(x, Wt, b, out);
    } else {
        int total = BROWS * SPLITN * UNITS;
        naive_lc<<<(total + 255) / 256, 256, 0, stream>>>(x, W, b, out, total);
    }
}